// Round 10
// baseline (90.701 us; speedup 1.0000x reference)
//
#include <hip/hip_runtime.h>
#include <stdint.h>

typedef _Float16 f16x8 __attribute__((ext_vector_type(8)));
typedef float f32x4 __attribute__((ext_vector_type(4)));

// ---------------------------------------------------------------------------
__device__ __forceinline__ void gload16(const void* g, void* l) {
  __builtin_amdgcn_global_load_lds((const __attribute__((address_space(1))) void*)g,
                                   (__attribute__((address_space(3))) void*)l,
                                   16, 0, 0);
}

// SS region mapping: padded 32-row groups, 30 valid (proven R3..R9)
__device__ __forceinline__ void maprow_ss(int gr, int& rowU, int& rowV, bool& ok) {
  int g = gr >> 5, p = gr & 31;
  ok = (p < 30);
  int i = p / 5, jj = p % 5;
  int j = jj + (jj >= i);
  rowU = g * 6 + j;
  rowV = g * 6 + i;
  if (!ok) { rowU = 0; rowV = 0; }
}

// SQ region mapping: DENSE 12-row groups (proven R9). gr in [0, 24576).
__device__ __forceinline__ void maprow_sq(int gr, int& rowU, int& rowV) {
  int h = gr / 12, p = gr % 12;
  int b = h >> 5, q = (h >> 1) & 15, wv = h & 1;
  int sbase = (b * 2 + wv) * 6;
  int qrow = 768 + b * 16 + q;
  if (p < 6) { rowU = qrow; rowV = sbase + p; }
  else       { rowU = sbase + (p - 6); rowV = qrow; }
}

__device__ __forceinline__ f16x8 cvt8h(float4 a, float4 b) {
  f16x8 o;
  o[0] = (_Float16)a.x; o[1] = (_Float16)a.y; o[2] = (_Float16)a.z; o[3] = (_Float16)a.w;
  o[4] = (_Float16)b.x; o[5] = (_Float16)b.y; o[6] = (_Float16)b.z; o[7] = (_Float16)b.w;
  return o;
}

// ---------------------------------------------------------------------------
// Weight transposes -> f16 (R7 proven) + out[] init to bf2 (for gemm3 atomics)
__global__ void convert_t(const float* __restrict__ Wg1, const float* __restrict__ Wg2,
                          const float* __restrict__ Wf1, const float* __restrict__ bf2,
                          _Float16* __restrict__ Wg1T, _Float16* __restrict__ Wg2T,
                          _Float16* __restrict__ Wf1T, float* __restrict__ out) {
  int tt = blockIdx.x * 256 + threadIdx.x;  // 512 blocks
  if (tt < 2048) out[tt] = bf2[0];
  const float* src;
  _Float16* dst;
  int c, k0, scol, srow0;
  if (tt < 65536) {
    c = tt & 1023; k0 = (tt >> 10) << 3;
    dst = Wg1T + (size_t)c * 512 + k0;
    if (c < 512) { src = Wg1; scol = c; srow0 = k0; }
    else         { src = Wg1; scol = c - 512; srow0 = 512 + k0; }
  } else if (tt < 98304) {
    int t2 = tt - 65536;
    c = t2 & 511; k0 = (t2 >> 9) << 3;
    dst = Wg2T + (size_t)c * 512 + k0;
    src = Wg2; scol = c; srow0 = k0;
  } else {
    int t3 = tt - 98304;
    c = t3 & 511; k0 = (t3 >> 9) << 3;
    dst = Wf1T + (size_t)c * 512 + k0;
    src = Wf1; scol = c; srow0 = k0;
  }
  f16x8 o;
#pragma unroll
  for (int i = 0; i < 8; i++)
    o[i] = (_Float16)src[(size_t)(srow0 + i) * 512 + scol];
  *(f16x8*)dst = o;
}

// ---------------------------------------------------------------------------
// Layer-1: UVh[1792][1024] = f16(x) @ Wg1T^T, bg1 folded into V-half cols.
// (R7/R8/R9 proven, unchanged)
__global__ __launch_bounds__(256, 2) void gemm1_fused(
    const float* __restrict__ xs, const float* __restrict__ xq,
    const _Float16* __restrict__ BT, const float* __restrict__ bg1,
    _Float16* __restrict__ UVh) {
  __shared__ __align__(16) char smem[24576];

  int bid = blockIdx.x;
  { int q = gridDim.x >> 3; bid = (bid & 7) * q + (bid >> 3); }  // 224 % 8 == 0
  const int tm = bid >> 4;
  const int tn = bid & 15;
  const int t = threadIdx.x, w = t >> 6, l = t & 63;
  const int wm = (w >> 1) << 6, wn = (w & 1) << 5;
  const int lr = l & 15, lg = l >> 4;

  const int rl0 = t >> 2, c = t & 3;
  const int wchunk = c ^ ((rl0 >> 2) & 3);
  const int gr0 = tm * 128 + rl0, gr1 = gr0 + 64;
  const float* x0 = ((gr0 < 768) ? xs + (size_t)gr0 * 512 : xq + (size_t)(gr0 - 768) * 512) + c * 8;
  const float* x1 = ((gr1 < 768) ? xs + (size_t)gr1 * 512 : xq + (size_t)(gr1 - 768) * 512) + c * 8;

  const int kch = ((t & 3) ^ ((t >> 4) & 3)) * 8;
  const _Float16* Bg = BT + (size_t)(tn * 64 + rl0) * 512 + kch;

  _Float16* As_base = (_Float16*)smem;
  char*     Bs_base = smem + 16384;

  f32x4 acc[4][2];
#pragma unroll
  for (int m = 0; m < 4; m++)
#pragma unroll
    for (int n = 0; n < 2; n++) acc[m][n] = (f32x4){0.f, 0.f, 0.f, 0.f};
  const int rchunk = (lg ^ (lr >> 2)) * 8;

  gload16(Bg, Bs_base + t * 16);
  {
    float4 a0 = *(const float4*)(x0), a1 = *(const float4*)(x0 + 4);
    float4 b0 = *(const float4*)(x1), b1 = *(const float4*)(x1 + 4);
    *(f16x8*)(As_base + rl0 * 32 + wchunk * 8) = cvt8h(a0, a1);
    *(f16x8*)(As_base + (rl0 + 64) * 32 + wchunk * 8) = cvt8h(b0, b1);
  }
  __syncthreads();

  int cur = 0;
  for (int it = 0; it < 15; ++it) {
    const int nxt = cur ^ 1;
    const int kn = (it + 1) * 32;
    gload16(Bg + kn, Bs_base + nxt * 4096 + t * 16);
    float4 a0 = *(const float4*)(x0 + kn), a1 = *(const float4*)(x0 + kn + 4);
    float4 b0 = *(const float4*)(x1 + kn), b1 = *(const float4*)(x1 + kn + 4);
    {
      _Float16* As = As_base + cur * 4096;
      _Float16* Bs = (_Float16*)(Bs_base + cur * 4096);
      f16x8 fa[4], fb[2];
#pragma unroll
      for (int m = 0; m < 4; m++)
        fa[m] = *(const f16x8*)(As + (wm + m * 16 + lr) * 32 + rchunk);
#pragma unroll
      for (int n = 0; n < 2; n++)
        fb[n] = *(const f16x8*)(Bs + (wn + n * 16 + lr) * 32 + rchunk);
#pragma unroll
      for (int m = 0; m < 4; m++)
#pragma unroll
        for (int n = 0; n < 2; n++)
          acc[m][n] = __builtin_amdgcn_mfma_f32_16x16x32_f16(fa[m], fb[n], acc[m][n], 0, 0, 0);
    }
    *(f16x8*)(As_base + nxt * 4096 + rl0 * 32 + wchunk * 8) = cvt8h(a0, a1);
    *(f16x8*)(As_base + nxt * 4096 + (rl0 + 64) * 32 + wchunk * 8) = cvt8h(b0, b1);
    __syncthreads();
    cur = nxt;
  }
  {
    _Float16* As = As_base + cur * 4096;
    _Float16* Bs = (_Float16*)(Bs_base + cur * 4096);
    f16x8 fa[4], fb[2];
#pragma unroll
    for (int m = 0; m < 4; m++)
      fa[m] = *(const f16x8*)(As + (wm + m * 16 + lr) * 32 + rchunk);
#pragma unroll
    for (int n = 0; n < 2; n++)
      fb[n] = *(const f16x8*)(Bs + (wn + n * 16 + lr) * 32 + rchunk);
#pragma unroll
    for (int m = 0; m < 4; m++)
#pragma unroll
      for (int n = 0; n < 2; n++)
        acc[m][n] = __builtin_amdgcn_mfma_f32_16x16x32_f16(fa[m], fb[n], acc[m][n], 0, 0, 0);
  }

#pragma unroll
  for (int m = 0; m < 4; m++)
#pragma unroll
    for (int n = 0; n < 2; n++) {
      int col = tn * 64 + wn + n * 16 + lr;
      float bv = (col >= 512) ? bg1[col - 512] : 0.0f;
#pragma unroll
      for (int reg = 0; reg < 4; reg++) {
        int row = tm * 128 + wm + m * 16 + lg * 4 + reg;
        UVh[(size_t)row * 1024 + col] = (_Float16)(acc[m][n][reg] + bv);
      }
    }
}

// ---------------------------------------------------------------------------
// Layer-2 SQ kernel: dense 96-row tiles, A-fragments built DIRECTLY in
// registers (no A LDS round-trip; fragment layout proven by the passing
// swizzle identity: lane(lr,lg) <-> A[16m+lr][k0+lg*8]). B via gload16 dbuf,
// counted-vmcnt raw barrier (R8-proven pattern). LDS = 16KB (B only).
__global__ __launch_bounds__(256, 2) void gemm2_sq(
    const _Float16* __restrict__ UVh,
    const _Float16* __restrict__ BT, const float* __restrict__ bg2,
    float* __restrict__ outSQ) {
  __shared__ __align__(16) char smem[16384];  // B[2] x 8KB

  int bid = blockIdx.x;
  { int q = gridDim.x >> 3; bid = (bid & 7) * q + (bid >> 3); }  // 1024 % 8 == 0
  const int tile = bid >> 2, tn = bid & 3;
  const int t = threadIdx.x, w = t >> 6, l = t & 63;
  const int lr = l & 15, lg = l >> 4;
  const int wm = (w >> 1) * 48, wn = (w & 1) << 6;
  const int rl = t >> 2;
  const int kch = ((t & 3) ^ ((t >> 4) & 3)) * 8;
  const int rchunk = (lg ^ (lr >> 2)) * 8;
  const f16x8 zz = {};

  // per-lane fragment row pointers (rows wm + m*16 + lr, k-chunk lg*8)
  const _Float16 *uf[3], *vf[3];
#pragma unroll
  for (int m = 0; m < 3; m++) {
    int rU, rV;
    maprow_sq(tile * 96 + wm + m * 16 + lr, rU, rV);
    uf[m] = UVh + (size_t)rU * 1024 + lg * 8;
    vf[m] = UVh + (size_t)rV * 1024 + 512 + lg * 8;
  }
  const _Float16* Bg = BT + (size_t)(tn * 128 + rl) * 512 + kch;

  f32x4 acc[3][4];
#pragma unroll
  for (int m = 0; m < 3; m++)
#pragma unroll
    for (int n = 0; n < 4; n++) acc[m][n] = (f32x4){0.f, 0.f, 0.f, 0.f};

  // prologue: B(0) DMA + uv(0) register loads
  gload16(Bg, smem + t * 16);
  gload16(Bg + (size_t)64 * 512, smem + 4096 + t * 16);
  f16x8 uc[3], vc[3];
#pragma unroll
  for (int m = 0; m < 3; m++) { uc[m] = *(const f16x8*)(uf[m]); vc[m] = *(const f16x8*)(vf[m]); }
  asm volatile("s_waitcnt vmcnt(6) lgkmcnt(0)" ::: "memory");  // drain B(0); uv in flight
  __builtin_amdgcn_s_barrier();
  asm volatile("" ::: "memory");

  for (int it = 0; it < 15; ++it) {
    const int kn = (it + 1) * 32;
    const int nxt = (it + 1) & 1;
    // issue B(it+1) DMA (2 vm entries), then uv(it+1) reg loads (6 entries)
    gload16(Bg + kn, smem + nxt * 8192 + t * 16);
    gload16(Bg + (size_t)64 * 512 + kn, smem + nxt * 8192 + 4096 + t * 16);
    f16x8 un[3], vn[3];
#pragma unroll
    for (int m = 0; m < 3; m++) { un[m] = *(const f16x8*)(uf[m] + kn); vn[m] = *(const f16x8*)(vf[m] + kn); }
    // compute current: fb from LDS, fa from registers
    {
      _Float16* Bs = (_Float16*)(smem + (it & 1) * 8192);
      f16x8 fb[4];
#pragma unroll
      for (int n = 0; n < 4; n++)
        fb[n] = *(const f16x8*)(Bs + (wn + n * 16 + lr) * 32 + rchunk);
      f16x8 fa[3];
#pragma unroll
      for (int m = 0; m < 3; m++) fa[m] = __builtin_elementwise_max(uc[m] + vc[m], zz);
#pragma unroll
      for (int m = 0; m < 3; m++)
#pragma unroll
        for (int n = 0; n < 4; n++)
          acc[m][n] = __builtin_amdgcn_mfma_f32_16x16x32_f16(fa[m], fb[n], acc[m][n], 0, 0, 0);
    }
    // counted barrier: drain B(it+1) (oldest 2), leave uv(it+1) in flight
    asm volatile("s_waitcnt vmcnt(6) lgkmcnt(0)" ::: "memory");
    __builtin_amdgcn_s_barrier();
    asm volatile("" ::: "memory");
#pragma unroll
    for (int m = 0; m < 3; m++) { uc[m] = un[m]; vc[m] = vn[m]; }
  }
  // peeled it=15
  {
    _Float16* Bs = (_Float16*)(smem + 8192);  // 15&1 == 1
    f16x8 fb[4];
#pragma unroll
    for (int n = 0; n < 4; n++)
      fb[n] = *(const f16x8*)(Bs + (wn + n * 16 + lr) * 32 + rchunk);
    f16x8 fa[3];
#pragma unroll
    for (int m = 0; m < 3; m++) fa[m] = __builtin_elementwise_max(uc[m] + vc[m], zz);
#pragma unroll
    for (int m = 0; m < 3; m++)
#pragma unroll
      for (int n = 0; n < 4; n++)
        acc[m][n] = __builtin_amdgcn_mfma_f32_16x16x32_f16(fa[m], fb[n], acc[m][n], 0, 0, 0);
  }
  __syncthreads();  // LDS free for epilogue scratch

  // epilogue (R9 proven): in-lane 4-row sums -> per-wave scratch -> gather
  float* scr = (float*)smem + w * 192;  // 12 blocks x 16 lr
#pragma unroll
  for (int n = 0; n < 4; n++) {
    int col = tn * 128 + wn + n * 16 + lr;
    float bv = bg2[col];
#pragma unroll
    for (int m = 0; m < 3; m++) {
      float s = 0.0f;
#pragma unroll
      for (int reg = 0; reg < 4; reg++)
        s += fmaxf(acc[m][n][reg] + bv, 0.0f);
      scr[(4 * m + lg) * 16 + lr] = s;
    }
#pragma unroll
    for (int g = 0; g < 4; g++) {
      float vs = scr[(3 * g) * 16 + lr] + scr[(3 * g + 1) * 16 + lr] +
                 scr[(3 * g + 2) * 16 + lr];
      if (l < 16) {
        int hh = tile * 8 + ((wm == 48) ? 4 : 0) + g;
        outSQ[(size_t)hh * 512 + col] = vs;
      }
    }
  }
}

// ---------------------------------------------------------------------------
// Layer-2 SS kernel: padded 128-row tiles (R9 SS path verbatim), grid 128.
__global__ __launch_bounds__(256, 2) void gemm2_ss(
    const _Float16* __restrict__ UVh,
    const _Float16* __restrict__ BT, const float* __restrict__ bg2,
    float* __restrict__ outSS) {
  __shared__ __align__(16) char smem[32768];

  int bid = blockIdx.x;
  { int q = gridDim.x >> 3; bid = (bid & 7) * q + (bid >> 3); }  // 128 % 8 == 0
  const int tm = bid >> 2, tn = bid & 3;
  const int t = threadIdx.x, w = t >> 6, l = t & 63;
  const int lr = l & 15, lg = l >> 4;
  const int wm = (w >> 1) << 6, wn = (w & 1) << 6;
  const int rl = t >> 2, c = t & 3;
  const int wchunk = c ^ ((t >> 4) & 3);
  const int kch = ((t & 3) ^ ((t >> 4) & 3)) * 8;
  const int rchunk = (lg ^ (lr >> 2)) * 8;
  const f16x8 zz = {};
  char* Bsb = smem + 16384;

  int rU0, rV0, rU1, rV1; bool ok0, ok1;
  maprow_ss(tm * 128 + rl, rU0, rV0, ok0);
  maprow_ss(tm * 128 + rl + 64, rU1, rV1, ok1);
  const _Float16* u0p = UVh + (size_t)rU0 * 1024 + c * 8;
  const _Float16* v0p = UVh + (size_t)rV0 * 1024 + 512 + c * 8;
  const _Float16* u1p = UVh + (size_t)rU1 * 1024 + c * 8;
  const _Float16* v1p = UVh + (size_t)rV1 * 1024 + 512 + c * 8;
  const _Float16* Bg = BT + (size_t)(tn * 128 + rl) * 512 + kch;

  f32x4 acc[4][4];
#pragma unroll
  for (int m = 0; m < 4; m++)
#pragma unroll
    for (int n = 0; n < 4; n++) acc[m][n] = (f32x4){0.f, 0.f, 0.f, 0.f};

  {
    f16x8 u0 = *(const f16x8*)(u0p), v0 = *(const f16x8*)(v0p);
    f16x8 u1 = *(const f16x8*)(u1p), v1 = *(const f16x8*)(v1p);
    f16x8 o0 = ok0 ? __builtin_elementwise_max(u0 + v0, zz) : zz;
    f16x8 o1 = ok1 ? __builtin_elementwise_max(u1 + v1, zz) : zz;
    *(f16x8*)((_Float16*)smem + rl * 32 + wchunk * 8) = o0;
    *(f16x8*)((_Float16*)smem + (rl + 64) * 32 + wchunk * 8) = o1;
  }
  gload16(Bg, Bsb + t * 16);
  gload16(Bg + (size_t)64 * 512, Bsb + 4096 + t * 16);
  __syncthreads();

  int cur = 0;
  for (int it = 0; it < 15; ++it) {
    const int nxt = cur ^ 1;
    const int kn = (it + 1) * 32;
    gload16(Bg + kn, Bsb + nxt * 8192 + t * 16);
    gload16(Bg + (size_t)64 * 512 + kn, Bsb + nxt * 8192 + 4096 + t * 16);
    f16x8 u0 = *(const f16x8*)(u0p + kn), v0 = *(const f16x8*)(v0p + kn);
    f16x8 u1 = *(const f16x8*)(u1p + kn), v1 = *(const f16x8*)(v1p + kn);
    {
      _Float16* As = (_Float16*)(smem + cur * 8192);
      _Float16* Bs = (_Float16*)(Bsb + cur * 8192);
      f16x8 fa[4], fb[4];
#pragma unroll
      for (int m = 0; m < 4; m++)
        fa[m] = *(const f16x8*)(As + (wm + m * 16 + lr) * 32 + rchunk);
#pragma unroll
      for (int n = 0; n < 4; n++)
        fb[n] = *(const f16x8*)(Bs + (wn + n * 16 + lr) * 32 + rchunk);
#pragma unroll
      for (int m = 0; m < 4; m++)
#pragma unroll
        for (int n = 0; n < 4; n++)
          acc[m][n] = __builtin_amdgcn_mfma_f32_16x16x32_f16(fa[m], fb[n], acc[m][n], 0, 0, 0);
    }
    {
      f16x8 o0 = ok0 ? __builtin_elementwise_max(u0 + v0, zz) : zz;
      f16x8 o1 = ok1 ? __builtin_elementwise_max(u1 + v1, zz) : zz;
      _Float16* Aw = (_Float16*)(smem + nxt * 8192);
      *(f16x8*)(Aw + rl * 32 + wchunk * 8) = o0;
      *(f16x8*)(Aw + (rl + 64) * 32 + wchunk * 8) = o1;
    }
    __syncthreads();
    cur = nxt;
  }
  {
    _Float16* As = (_Float16*)(smem + cur * 8192);
    _Float16* Bs = (_Float16*)(Bsb + cur * 8192);
    f16x8 fa[4], fb[4];
#pragma unroll
    for (int m = 0; m < 4; m++)
      fa[m] = *(const f16x8*)(As + (wm + m * 16 + lr) * 32 + rchunk);
#pragma unroll
    for (int n = 0; n < 4; n++)
      fb[n] = *(const f16x8*)(Bs + (wn + n * 16 + lr) * 32 + rchunk);
#pragma unroll
    for (int m = 0; m < 4; m++)
#pragma unroll
      for (int n = 0; n < 4; n++)
        acc[m][n] = __builtin_amdgcn_mfma_f32_16x16x32_f16(fa[m], fb[n], acc[m][n], 0, 0, 0);
  }

#pragma unroll
  for (int pair = 0; pair < 2; pair++) {
#pragma unroll
    for (int n = 0; n < 4; n++) {
      int col = tn * 128 + wn + n * 16 + lr;
      float bv = bg2[col];
      float s = 0.0f;
#pragma unroll
      for (int mh = 0; mh < 2; mh++) {
        int m = pair * 2 + mh;
#pragma unroll
        for (int reg = 0; reg < 4; reg++) {
          bool ok = (mh == 0) || (lg * 4 + reg < 14);
          float v = fmaxf(acc[m][n][reg] + bv, 0.0f);
          s += ok ? v : 0.0f;
        }
      }
      s += __shfl_xor(s, 16);
      s += __shfl_xor(s, 32);
      if (l < 16) {
        int g = (wm >> 5) + pair;
        outSS[(size_t)(tm * 4 + g) * 512 + col] = s;
      }
    }
  }
}

// ---------------------------------------------------------------------------
// Layer-3 + final dot fused (R9 proven, unchanged)
__global__ __launch_bounds__(256, 2) void gemm3_fused(
    const float* __restrict__ SS, const float* __restrict__ SQ,
    const _Float16* __restrict__ BT, const float* __restrict__ bf1,
    const float* __restrict__ Wf2, float* __restrict__ out) {
  __shared__ __align__(16) char smem[24576];

  int bid = blockIdx.x;
  { int q = gridDim.x >> 3; bid = (bid & 7) * q + (bid >> 3); }  // 128 % 8 == 0
  const int tm = bid >> 3;
  const int tn = bid & 7;
  const int t = threadIdx.x, w = t >> 6, l = t & 63;
  const int wm = (w >> 1) << 6, wn = (w & 1) << 5;
  const int lr = l & 15, lg = l >> 4;

  const int rl0 = t >> 2, c = t & 3;
  const int wchunk = c ^ ((rl0 >> 2) & 3);
  const int gr0 = tm * 128 + rl0, gr1 = gr0 + 64;
  const int ss0 = (gr0 >> 5) * 2 + (gr0 & 1);
  const int ss1 = (gr1 >> 5) * 2 + (gr1 & 1);
  const float* s0p = SS + (size_t)ss0 * 512 + c * 8;
  const float* q0p = SQ + (size_t)gr0 * 512 + c * 8;
  const float* s1p = SS + (size_t)ss1 * 512 + c * 8;
  const float* q1p = SQ + (size_t)gr1 * 512 + c * 8;

  const int kch = ((t & 3) ^ ((t >> 4) & 3)) * 8;
  const _Float16* Bg = BT + (size_t)(tn * 64 + rl0) * 512 + kch;

  _Float16* As_base = (_Float16*)smem;
  char*     Bs_base = smem + 16384;

  f32x4 acc[4][2];
#pragma unroll
  for (int m = 0; m < 4; m++)
#pragma unroll
    for (int n = 0; n < 2; n++) acc[m][n] = (f32x4){0.f, 0.f, 0.f, 0.f};
  const int rchunk = (lg ^ (lr >> 2)) * 8;

#define BUILD_S(o, a0, a1, b0, b1)                                           \
  {                                                                          \
    o[0] = (_Float16)(a0.x + b0.x); o[1] = (_Float16)(a0.y + b0.y);          \
    o[2] = (_Float16)(a0.z + b0.z); o[3] = (_Float16)(a0.w + b0.w);          \
    o[4] = (_Float16)(a1.x + b1.x); o[5] = (_Float16)(a1.y + b1.y);          \
    o[6] = (_Float16)(a1.z + b1.z); o[7] = (_Float16)(a1.w + b1.w);          \
  }

  gload16(Bg, Bs_base + t * 16);
  {
    float4 a0 = *(const float4*)(s0p), a1 = *(const float4*)(s0p + 4);
    float4 b0 = *(const float4*)(q0p), b1 = *(const float4*)(q0p + 4);
    float4 c0 = *(const float4*)(s1p), c1 = *(const float4*)(s1p + 4);
    float4 d0 = *(const float4*)(q1p), d1 = *(const float4*)(q1p + 4);
    f16x8 o0, o1;
    BUILD_S(o0, a0, a1, b0, b1);
    BUILD_S(o1, c0, c1, d0, d1);
    *(f16x8*)(As_base + rl0 * 32 + wchunk * 8) = o0;
    *(f16x8*)(As_base + (rl0 + 64) * 32 + wchunk * 8) = o1;
  }
  __syncthreads();

  int cur = 0;
  for (int it = 0; it < 15; ++it) {
    const int nxt = cur ^ 1;
    const int kn = (it + 1) * 32;
    gload16(Bg + kn, Bs_base + nxt * 4096 + t * 16);
    float4 a0 = *(const float4*)(s0p + kn), a1 = *(const float4*)(s0p + kn + 4);
    float4 b0 = *(const float4*)(q0p + kn), b1 = *(const float4*)(q0p + kn + 4);
    float4 c0 = *(const float4*)(s1p + kn), c1 = *(const float4*)(s1p + kn + 4);
    float4 d0 = *(const float4*)(q1p + kn), d1 = *(const float4*)(q1p + kn + 4);
    {
      _Float16* As = As_base + cur * 4096;
      _Float16* Bs = (_Float16*)(Bs_base + cur * 4096);
      f16x8 fa[4], fb[2];
#pragma unroll
      for (int m = 0; m < 4; m++)
        fa[m] = *(const f16x8*)(As + (wm + m * 16 + lr) * 32 + rchunk);
#pragma unroll
      for (int n = 0; n < 2; n++)
        fb[n] = *(const f16x8*)(Bs + (wn + n * 16 + lr) * 32 + rchunk);
#pragma unroll
      for (int m = 0; m < 4; m++)
#pragma unroll
        for (int n = 0; n < 2; n++)
          acc[m][n] = __builtin_amdgcn_mfma_f32_16x16x32_f16(fa[m], fb[n], acc[m][n], 0, 0, 0);
    }
    {
      f16x8 o0, o1;
      BUILD_S(o0, a0, a1, b0, b1);
      BUILD_S(o1, c0, c1, d0, d1);
      *(f16x8*)(As_base + nxt * 4096 + rl0 * 32 + wchunk * 8) = o0;
      *(f16x8*)(As_base + nxt * 4096 + (rl0 + 64) * 32 + wchunk * 8) = o1;
    }
    __syncthreads();
    cur = nxt;
  }
  {
    _Float16* As = As_base + cur * 4096;
    _Float16* Bs = (_Float16*)(Bs_base + cur * 4096);
    f16x8 fa[4], fb[2];
#pragma unroll
    for (int m = 0; m < 4; m++)
      fa[m] = *(const f16x8*)(As + (wm + m * 16 + lr) * 32 + rchunk);
#pragma unroll
    for (int n = 0; n < 2; n++)
      fb[n] = *(const f16x8*)(Bs + (wn + n * 16 + lr) * 32 + rchunk);
#pragma unroll
    for (int m = 0; m < 4; m++)
#pragma unroll
      for (int n = 0; n < 2; n++)
        acc[m][n] = __builtin_amdgcn_mfma_f32_16x16x32_f16(fa[m], fb[n], acc[m][n], 0, 0, 0);
  }

  float bf1v[2], wf2v[2];
#pragma unroll
  for (int n = 0; n < 2; n++) {
    int col = tn * 64 + wn + n * 16 + lr;
    bf1v[n] = bf1[col];
    wf2v[n] = Wf2[col];
  }
#pragma unroll
  for (int m = 0; m < 4; m++) {
#pragma unroll
    for (int reg = 0; reg < 4; reg++) {
      float p = 0.0f;
#pragma unroll
      for (int n = 0; n < 2; n++)
        p += fmaxf(acc[m][n][reg] + bf1v[n], 0.0f) * wf2v[n];
      p += __shfl_xor(p, 1);
      p += __shfl_xor(p, 2);
      p += __shfl_xor(p, 4);
      p += __shfl_xor(p, 8);
      if (lr == 0) {
        int row = tm * 128 + wm + m * 16 + lg * 4 + reg;
        atomicAdd(&out[row], p);
      }
    }
  }
#undef BUILD_S
}

// ---------------------------------------------------------------------------
extern "C" void kernel_launch(void* const* d_in, const int* in_sizes, int n_in,
                              void* d_out, int out_size, void* d_ws, size_t ws_size,
                              hipStream_t stream) {
  const float* xs  = (const float*)d_in[0];
  const float* xq  = (const float*)d_in[1];
  const float* Wg1 = (const float*)d_in[2];
  const float* bg1 = (const float*)d_in[3];
  const float* Wg2 = (const float*)d_in[4];
  const float* bg2 = (const float*)d_in[5];
  const float* Wf1 = (const float*)d_in[6];
  const float* bf1 = (const float*)d_in[7];
  const float* Wf2 = (const float*)d_in[8];
  const float* bf2 = (const float*)d_in[9];
  float* out = (float*)d_out;

  char* ws = (char*)d_ws;
  _Float16* Wg1T = (_Float16*)(ws);             // 1,048,576
  _Float16* Wg2T = (_Float16*)(ws + 1048576);   //   524,288
  _Float16* Wf1T = (_Float16*)(ws + 1572864);   //   524,288
  _Float16* UVh  = (_Float16*)(ws + 2097152);   // 3,670,016
  float*    SSs  = (float*)(ws + 5767168);      //   262,144
  float*    SQs  = (float*)(ws + 6029312);      // 4,194,304

  convert_t<<<512, 256, 0, stream>>>(Wg1, Wg2, Wf1, bf2, Wg1T, Wg2T, Wf1T, out);
  gemm1_fused<<<224, 256, 0, stream>>>(xs, xq, Wg1T, bg1, UVh);
  gemm2_sq<<<1024, 256, 0, stream>>>(UVh, Wg2T, bg2, SQs);
  gemm2_ss<<<128, 256, 0, stream>>>(UVh, Wg2T, bg2, SSs);
  gemm3_fused<<<128, 256, 0, stream>>>(SSs, SQs, Wf1T, bf1, Wf2, out);
}

// Round 11
// 61.330 us; speedup vs baseline: 1.4789x; 1.4789x over previous
//
#include <hip/hip_runtime.h>
#include <stdint.h>

typedef _Float16 f16x8 __attribute__((ext_vector_type(8)));
typedef float f32x4 __attribute__((ext_vector_type(4)));

// ---------------------------------------------------------------------------
__device__ __forceinline__ void gload16(const void* g, void* l) {
  __builtin_amdgcn_global_load_lds((const __attribute__((address_space(1))) void*)g,
                                   (__attribute__((address_space(3))) void*)l,
                                   16, 0, 0);
}

// SS region mapping: padded 32-row groups, 30 valid (proven R3..R9)
__device__ __forceinline__ void maprow_ss(int gr, int& rowU, int& rowV, bool& ok) {
  int g = gr >> 5, p = gr & 31;
  ok = (p < 30);
  int i = p / 5, jj = p % 5;
  int j = jj + (jj >= i);
  rowU = g * 6 + j;
  rowV = g * 6 + i;
  if (!ok) { rowU = 0; rowV = 0; }
}

// SQ region mapping: DENSE 12-row groups (proven R9). gr in [0, 24576).
__device__ __forceinline__ void maprow_sq(int gr, int& rowU, int& rowV) {
  int h = gr / 12, p = gr % 12;
  int b = h >> 5, q = (h >> 1) & 15, wv = h & 1;
  int sbase = (b * 2 + wv) * 6;
  int qrow = 768 + b * 16 + q;
  if (p < 6) { rowU = qrow; rowV = sbase + p; }
  else       { rowU = sbase + (p - 6); rowV = qrow; }
}

__device__ __forceinline__ f16x8 cvt8h(float4 a, float4 b) {
  f16x8 o;
  o[0] = (_Float16)a.x; o[1] = (_Float16)a.y; o[2] = (_Float16)a.z; o[3] = (_Float16)a.w;
  o[4] = (_Float16)b.x; o[5] = (_Float16)b.y; o[6] = (_Float16)b.z; o[7] = (_Float16)b.w;
  return o;
}

// ---------------------------------------------------------------------------
// Weight transposes -> f16 (R7 proven) + out[] init to bf2 (for gemm3 atomics)
__global__ void convert_t(const float* __restrict__ Wg1, const float* __restrict__ Wg2,
                          const float* __restrict__ Wf1, const float* __restrict__ bf2,
                          _Float16* __restrict__ Wg1T, _Float16* __restrict__ Wg2T,
                          _Float16* __restrict__ Wf1T, float* __restrict__ out) {
  int tt = blockIdx.x * 256 + threadIdx.x;  // 512 blocks
  if (tt < 2048) out[tt] = bf2[0];
  const float* src;
  _Float16* dst;
  int c, k0, scol, srow0;
  if (tt < 65536) {
    c = tt & 1023; k0 = (tt >> 10) << 3;
    dst = Wg1T + (size_t)c * 512 + k0;
    if (c < 512) { src = Wg1; scol = c; srow0 = k0; }
    else         { src = Wg1; scol = c - 512; srow0 = 512 + k0; }
  } else if (tt < 98304) {
    int t2 = tt - 65536;
    c = t2 & 511; k0 = (t2 >> 9) << 3;
    dst = Wg2T + (size_t)c * 512 + k0;
    src = Wg2; scol = c; srow0 = k0;
  } else {
    int t3 = tt - 98304;
    c = t3 & 511; k0 = (t3 >> 9) << 3;
    dst = Wf1T + (size_t)c * 512 + k0;
    src = Wf1; scol = c; srow0 = k0;
  }
  f16x8 o;
#pragma unroll
  for (int i = 0; i < 8; i++)
    o[i] = (_Float16)src[(size_t)(srow0 + i) * 512 + scol];
  *(f16x8*)dst = o;
}

// ---------------------------------------------------------------------------
// Layer-1: UVh[1792][1024] = f16(x) @ Wg1T^T, bg1 folded into V-half cols.
// Retiled 64x64 (grid 448 = 1.75 blocks/CU), wave tile 32x32 (acc[2][2]).
// One A-row slot per thread. All formulas = proven instances, bounds halved.
__global__ __launch_bounds__(256, 2) void gemm1_fused(
    const float* __restrict__ xs, const float* __restrict__ xq,
    const _Float16* __restrict__ BT, const float* __restrict__ bg1,
    _Float16* __restrict__ UVh) {
  __shared__ __align__(16) char smem[16384];  // As[2] 8K @0, Bs[2] 8K @8192

  int bid = blockIdx.x;
  { int q = gridDim.x >> 3; bid = (bid & 7) * q + (bid >> 3); }  // 448 % 8 == 0
  const int tm = bid >> 4;   // 0..27
  const int tn = bid & 15;   // 0..15
  const int t = threadIdx.x, w = t >> 6, l = t & 63;
  const int wm = (w >> 1) << 5, wn = (w & 1) << 5;
  const int lr = l & 15, lg = l >> 4;

  const int rl0 = t >> 2, c = t & 3;
  const int wchunk = c ^ ((rl0 >> 2) & 3);
  const int gr0 = tm * 64 + rl0;
  const float* x0 = ((gr0 < 768) ? xs + (size_t)gr0 * 512 : xq + (size_t)(gr0 - 768) * 512) + c * 8;

  const int kch = ((t & 3) ^ ((t >> 4) & 3)) * 8;
  const _Float16* Bg = BT + (size_t)(tn * 64 + rl0) * 512 + kch;

  _Float16* As_base = (_Float16*)smem;  // + cur*2048 elems
  char*     Bs_base = smem + 8192;      // + cur*4096 bytes

  f32x4 acc[2][2];
#pragma unroll
  for (int m = 0; m < 2; m++)
#pragma unroll
    for (int n = 0; n < 2; n++) acc[m][n] = (f32x4){0.f, 0.f, 0.f, 0.f};
  const int rchunk = (lg ^ (lr >> 2)) * 8;

  gload16(Bg, Bs_base + t * 16);
  {
    float4 a0 = *(const float4*)(x0), a1 = *(const float4*)(x0 + 4);
    *(f16x8*)(As_base + rl0 * 32 + wchunk * 8) = cvt8h(a0, a1);
  }
  __syncthreads();

  int cur = 0;
  for (int it = 0; it < 15; ++it) {
    const int nxt = cur ^ 1;
    const int kn = (it + 1) * 32;
    gload16(Bg + kn, Bs_base + nxt * 4096 + t * 16);
    float4 a0 = *(const float4*)(x0 + kn), a1 = *(const float4*)(x0 + kn + 4);
    {
      _Float16* As = As_base + cur * 2048;
      _Float16* Bs = (_Float16*)(Bs_base + cur * 4096);
      f16x8 fa[2], fb[2];
#pragma unroll
      for (int m = 0; m < 2; m++)
        fa[m] = *(const f16x8*)(As + (wm + m * 16 + lr) * 32 + rchunk);
#pragma unroll
      for (int n = 0; n < 2; n++)
        fb[n] = *(const f16x8*)(Bs + (wn + n * 16 + lr) * 32 + rchunk);
#pragma unroll
      for (int m = 0; m < 2; m++)
#pragma unroll
        for (int n = 0; n < 2; n++)
          acc[m][n] = __builtin_amdgcn_mfma_f32_16x16x32_f16(fa[m], fb[n], acc[m][n], 0, 0, 0);
    }
    *(f16x8*)(As_base + nxt * 2048 + rl0 * 32 + wchunk * 8) = cvt8h(a0, a1);
    __syncthreads();
    cur = nxt;
  }
  {
    _Float16* As = As_base + cur * 2048;
    _Float16* Bs = (_Float16*)(Bs_base + cur * 4096);
    f16x8 fa[2], fb[2];
#pragma unroll
    for (int m = 0; m < 2; m++)
      fa[m] = *(const f16x8*)(As + (wm + m * 16 + lr) * 32 + rchunk);
#pragma unroll
    for (int n = 0; n < 2; n++)
      fb[n] = *(const f16x8*)(Bs + (wn + n * 16 + lr) * 32 + rchunk);
#pragma unroll
    for (int m = 0; m < 2; m++)
#pragma unroll
      for (int n = 0; n < 2; n++)
        acc[m][n] = __builtin_amdgcn_mfma_f32_16x16x32_f16(fa[m], fb[n], acc[m][n], 0, 0, 0);
  }

#pragma unroll
  for (int m = 0; m < 2; m++)
#pragma unroll
    for (int n = 0; n < 2; n++) {
      int col = tn * 64 + wn + n * 16 + lr;
      float bv = (col >= 512) ? bg1[col - 512] : 0.0f;
#pragma unroll
      for (int reg = 0; reg < 4; reg++) {
        int row = tm * 64 + wm + m * 16 + lg * 4 + reg;
        UVh[(size_t)row * 1024 + col] = (_Float16)(acc[m][n][reg] + bv);
      }
    }
}

// ---------------------------------------------------------------------------
// Layer-2 (R9 proven, reverted verbatim): two block regions in one kernel.
//  bid <  1024: SQ, DENSE 96-row tiles (8 groups x 12 rows, no padding).
//  bid >= 1024: SS, padded 128-row tiles.
__global__ __launch_bounds__(256, 2) void gemm2_fused(
    const _Float16* __restrict__ UVh,
    const _Float16* __restrict__ BT, const float* __restrict__ bg2,
    float* __restrict__ outSS, float* __restrict__ outSQ) {
  __shared__ __align__(16) char smem[32768];

  int bid = blockIdx.x;
  { int q = gridDim.x >> 3; bid = (bid & 7) * q + (bid >> 3); }  // 1152 % 8 == 0
  const int t = threadIdx.x, w = t >> 6, l = t & 63;
  const int lr = l & 15, lg = l >> 4;
  const int rl = t >> 2, c = t & 3;
  const int wchunk = c ^ ((t >> 4) & 3);
  const int kch = ((t & 3) ^ ((t >> 4) & 3)) * 8;
  const int rchunk = (lg ^ (lr >> 2)) * 8;
  const f16x8 zz = {};
  char* Bsb = smem + 16384;  // B[2] x 8KB for both regions

  if (bid < 1024) {
    // ------------------- SQ region: dense 96-row tiles -------------------
    const int tile = bid >> 2, tn = bid & 3;
    const int wm = (w >> 1) * 48, wn = (w & 1) << 6;

    int rU0, rV0, rU1 = 0, rV1 = 0;
    maprow_sq(tile * 96 + rl, rU0, rV0);
    if (t < 128) maprow_sq(tile * 96 + 64 + rl, rU1, rV1);
    const _Float16* u0p = UVh + (size_t)rU0 * 1024 + c * 8;
    const _Float16* v0p = UVh + (size_t)rV0 * 1024 + 512 + c * 8;
    const _Float16* u1p = UVh + (size_t)rU1 * 1024 + c * 8;
    const _Float16* v1p = UVh + (size_t)rV1 * 1024 + 512 + c * 8;
    const _Float16* Bg = BT + (size_t)(tn * 128 + rl) * 512 + kch;

    f32x4 acc[3][4];
#pragma unroll
    for (int m = 0; m < 3; m++)
#pragma unroll
      for (int n = 0; n < 4; n++) acc[m][n] = (f32x4){0.f, 0.f, 0.f, 0.f};

    {
      f16x8 u0 = *(const f16x8*)(u0p), v0 = *(const f16x8*)(v0p);
      *(f16x8*)((_Float16*)smem + rl * 32 + wchunk * 8) =
          __builtin_elementwise_max(u0 + v0, zz);
      if (t < 128) {
        f16x8 u1 = *(const f16x8*)(u1p), v1 = *(const f16x8*)(v1p);
        *(f16x8*)((_Float16*)smem + (64 + rl) * 32 + wchunk * 8) =
            __builtin_elementwise_max(u1 + v1, zz);
      }
    }
    gload16(Bg, Bsb + t * 16);
    gload16(Bg + (size_t)64 * 512, Bsb + 4096 + t * 16);
    __syncthreads();

    int cur = 0;
    for (int it = 0; it < 15; ++it) {
      const int nxt = cur ^ 1;
      const int kn = (it + 1) * 32;
      gload16(Bg + kn, Bsb + nxt * 8192 + t * 16);
      gload16(Bg + (size_t)64 * 512 + kn, Bsb + nxt * 8192 + 4096 + t * 16);
      f16x8 u0 = *(const f16x8*)(u0p + kn), v0 = *(const f16x8*)(v0p + kn);
      f16x8 u1, v1;
      if (t < 128) { u1 = *(const f16x8*)(u1p + kn); v1 = *(const f16x8*)(v1p + kn); }
      {
        _Float16* As = (_Float16*)(smem + cur * 6144);
        _Float16* Bs = (_Float16*)(Bsb + cur * 8192);
        f16x8 fa[3], fb[4];
#pragma unroll
        for (int m = 0; m < 3; m++)
          fa[m] = *(const f16x8*)(As + (wm + m * 16 + lr) * 32 + rchunk);
#pragma unroll
        for (int n = 0; n < 4; n++)
          fb[n] = *(const f16x8*)(Bs + (wn + n * 16 + lr) * 32 + rchunk);
#pragma unroll
        for (int m = 0; m < 3; m++)
#pragma unroll
          for (int n = 0; n < 4; n++)
            acc[m][n] = __builtin_amdgcn_mfma_f32_16x16x32_f16(fa[m], fb[n], acc[m][n], 0, 0, 0);
      }
      {
        _Float16* Aw = (_Float16*)(smem + nxt * 6144);
        *(f16x8*)(Aw + rl * 32 + wchunk * 8) = __builtin_elementwise_max(u0 + v0, zz);
        if (t < 128)
          *(f16x8*)(Aw + (64 + rl) * 32 + wchunk * 8) = __builtin_elementwise_max(u1 + v1, zz);
      }
      __syncthreads();
      cur = nxt;
    }
    {
      _Float16* As = (_Float16*)(smem + cur * 6144);
      _Float16* Bs = (_Float16*)(Bsb + cur * 8192);
      f16x8 fa[3], fb[4];
#pragma unroll
      for (int m = 0; m < 3; m++)
        fa[m] = *(const f16x8*)(As + (wm + m * 16 + lr) * 32 + rchunk);
#pragma unroll
      for (int n = 0; n < 4; n++)
        fb[n] = *(const f16x8*)(Bs + (wn + n * 16 + lr) * 32 + rchunk);
#pragma unroll
      for (int m = 0; m < 3; m++)
#pragma unroll
        for (int n = 0; n < 4; n++)
          acc[m][n] = __builtin_amdgcn_mfma_f32_16x16x32_f16(fa[m], fb[n], acc[m][n], 0, 0, 0);
    }
    __syncthreads();  // LDS now free for epilogue scratch

    float* scr = (float*)smem + w * 192;  // 12 blocks x 16 lr
#pragma unroll
    for (int n = 0; n < 4; n++) {
      int col = tn * 128 + wn + n * 16 + lr;
      float bv = bg2[col];
#pragma unroll
      for (int m = 0; m < 3; m++) {
        float s = 0.0f;
#pragma unroll
        for (int reg = 0; reg < 4; reg++)
          s += fmaxf(acc[m][n][reg] + bv, 0.0f);
        scr[(4 * m + lg) * 16 + lr] = s;
      }
#pragma unroll
      for (int g = 0; g < 4; g++) {
        float vs = scr[(3 * g) * 16 + lr] + scr[(3 * g + 1) * 16 + lr] +
                   scr[(3 * g + 2) * 16 + lr];
        if (l < 16) {
          int hh = tile * 8 + ((wm == 48) ? 4 : 0) + g;
          outSQ[(size_t)hh * 512 + col] = vs;
        }
      }
    }
  } else {
    // ------------------- SS region: padded path -------------------
    const int sbid = bid - 1024;
    const int tm = sbid >> 2, tn = sbid & 3;
    const int wm = (w >> 1) << 6, wn = (w & 1) << 6;

    int rU0, rV0, rU1, rV1; bool ok0, ok1;
    maprow_ss(tm * 128 + rl, rU0, rV0, ok0);
    maprow_ss(tm * 128 + rl + 64, rU1, rV1, ok1);
    const _Float16* u0p = UVh + (size_t)rU0 * 1024 + c * 8;
    const _Float16* v0p = UVh + (size_t)rV0 * 1024 + 512 + c * 8;
    const _Float16* u1p = UVh + (size_t)rU1 * 1024 + c * 8;
    const _Float16* v1p = UVh + (size_t)rV1 * 1024 + 512 + c * 8;
    const _Float16* Bg = BT + (size_t)(tn * 128 + rl) * 512 + kch;

    f32x4 acc[4][4];
#pragma unroll
    for (int m = 0; m < 4; m++)
#pragma unroll
      for (int n = 0; n < 4; n++) acc[m][n] = (f32x4){0.f, 0.f, 0.f, 0.f};

    {
      f16x8 u0 = *(const f16x8*)(u0p), v0 = *(const f16x8*)(v0p);
      f16x8 u1 = *(const f16x8*)(u1p), v1 = *(const f16x8*)(v1p);
      f16x8 o0 = ok0 ? __builtin_elementwise_max(u0 + v0, zz) : zz;
      f16x8 o1 = ok1 ? __builtin_elementwise_max(u1 + v1, zz) : zz;
      *(f16x8*)((_Float16*)smem + rl * 32 + wchunk * 8) = o0;
      *(f16x8*)((_Float16*)smem + (rl + 64) * 32 + wchunk * 8) = o1;
    }
    gload16(Bg, Bsb + t * 16);
    gload16(Bg + (size_t)64 * 512, Bsb + 4096 + t * 16);
    __syncthreads();

    int cur = 0;
    for (int it = 0; it < 15; ++it) {
      const int nxt = cur ^ 1;
      const int kn = (it + 1) * 32;
      gload16(Bg + kn, Bsb + nxt * 8192 + t * 16);
      gload16(Bg + (size_t)64 * 512 + kn, Bsb + nxt * 8192 + 4096 + t * 16);
      f16x8 u0 = *(const f16x8*)(u0p + kn), v0 = *(const f16x8*)(v0p + kn);
      f16x8 u1 = *(const f16x8*)(u1p + kn), v1 = *(const f16x8*)(v1p + kn);
      {
        _Float16* As = (_Float16*)(smem + cur * 8192);
        _Float16* Bs = (_Float16*)(Bsb + cur * 8192);
        f16x8 fa[4], fb[4];
#pragma unroll
        for (int m = 0; m < 4; m++)
          fa[m] = *(const f16x8*)(As + (wm + m * 16 + lr) * 32 + rchunk);
#pragma unroll
        for (int n = 0; n < 4; n++)
          fb[n] = *(const f16x8*)(Bs + (wn + n * 16 + lr) * 32 + rchunk);
#pragma unroll
        for (int m = 0; m < 4; m++)
#pragma unroll
          for (int n = 0; n < 4; n++)
            acc[m][n] = __builtin_amdgcn_mfma_f32_16x16x32_f16(fa[m], fb[n], acc[m][n], 0, 0, 0);
      }
      {
        f16x8 o0 = ok0 ? __builtin_elementwise_max(u0 + v0, zz) : zz;
        f16x8 o1 = ok1 ? __builtin_elementwise_max(u1 + v1, zz) : zz;
        _Float16* Aw = (_Float16*)(smem + nxt * 8192);
        *(f16x8*)(Aw + rl * 32 + wchunk * 8) = o0;
        *(f16x8*)(Aw + (rl + 64) * 32 + wchunk * 8) = o1;
      }
      __syncthreads();
      cur = nxt;
    }
    {
      _Float16* As = (_Float16*)(smem + cur * 8192);
      _Float16* Bs = (_Float16*)(Bsb + cur * 8192);
      f16x8 fa[4], fb[4];
#pragma unroll
      for (int m = 0; m < 4; m++)
        fa[m] = *(const f16x8*)(As + (wm + m * 16 + lr) * 32 + rchunk);
#pragma unroll
      for (int n = 0; n < 4; n++)
        fb[n] = *(const f16x8*)(Bs + (wn + n * 16 + lr) * 32 + rchunk);
#pragma unroll
      for (int m = 0; m < 4; m++)
#pragma unroll
        for (int n = 0; n < 4; n++)
          acc[m][n] = __builtin_amdgcn_mfma_f32_16x16x32_f16(fa[m], fb[n], acc[m][n], 0, 0, 0);
    }

#pragma unroll
    for (int pair = 0; pair < 2; pair++) {
#pragma unroll
      for (int n = 0; n < 4; n++) {
        int col = tn * 128 + wn + n * 16 + lr;
        float bv = bg2[col];
        float s = 0.0f;
#pragma unroll
        for (int mh = 0; mh < 2; mh++) {
          int m = pair * 2 + mh;
#pragma unroll
          for (int reg = 0; reg < 4; reg++) {
            bool ok = (mh == 0) || (lg * 4 + reg < 14);
            float v = fmaxf(acc[m][n][reg] + bv, 0.0f);
            s += ok ? v : 0.0f;
          }
        }
        s += __shfl_xor(s, 16);
        s += __shfl_xor(s, 32);
        if (l < 16) {
          int g = (wm >> 5) + pair;
          outSS[(size_t)(tm * 4 + g) * 512 + col] = s;
        }
      }
    }
  }
}

// ---------------------------------------------------------------------------
// Layer-3 + final dot fused, retiled 64x64 (grid 256 = 1 block/CU), wave tile
// 32x32 (acc[2][2]). One A-row slot per thread. Epilogue: partial logits
// atomicAdd'ed into out[] (pre-init to bf2).
__global__ __launch_bounds__(256, 2) void gemm3_fused(
    const float* __restrict__ SS, const float* __restrict__ SQ,
    const _Float16* __restrict__ BT, const float* __restrict__ bf1,
    const float* __restrict__ Wf2, float* __restrict__ out) {
  __shared__ __align__(16) char smem[16384];  // As[2] 8K, Bs[2] 8K

  int bid = blockIdx.x;
  { int q = gridDim.x >> 3; bid = (bid & 7) * q + (bid >> 3); }  // 256 % 8 == 0
  const int tm = bid >> 3;   // 0..31
  const int tn = bid & 7;    // 0..7
  const int t = threadIdx.x, w = t >> 6, l = t & 63;
  const int wm = (w >> 1) << 5, wn = (w & 1) << 5;
  const int lr = l & 15, lg = l >> 4;

  const int rl0 = t >> 2, c = t & 3;
  const int wchunk = c ^ ((rl0 >> 2) & 3);
  const int gr0 = tm * 64 + rl0;
  const int ss0 = (gr0 >> 5) * 2 + (gr0 & 1);
  const float* s0p = SS + (size_t)ss0 * 512 + c * 8;
  const float* q0p = SQ + (size_t)gr0 * 512 + c * 8;

  const int kch = ((t & 3) ^ ((t >> 4) & 3)) * 8;
  const _Float16* Bg = BT + (size_t)(tn * 64 + rl0) * 512 + kch;

  _Float16* As_base = (_Float16*)smem;  // + cur*2048 elems
  char*     Bs_base = smem + 8192;      // + cur*4096 bytes

  f32x4 acc[2][2];
#pragma unroll
  for (int m = 0; m < 2; m++)
#pragma unroll
    for (int n = 0; n < 2; n++) acc[m][n] = (f32x4){0.f, 0.f, 0.f, 0.f};
  const int rchunk = (lg ^ (lr >> 2)) * 8;

#define BUILD_S(o, a0, a1, b0, b1)                                           \
  {                                                                          \
    o[0] = (_Float16)(a0.x + b0.x); o[1] = (_Float16)(a0.y + b0.y);          \
    o[2] = (_Float16)(a0.z + b0.z); o[3] = (_Float16)(a0.w + b0.w);          \
    o[4] = (_Float16)(a1.x + b1.x); o[5] = (_Float16)(a1.y + b1.y);          \
    o[6] = (_Float16)(a1.z + b1.z); o[7] = (_Float16)(a1.w + b1.w);          \
  }

  gload16(Bg, Bs_base + t * 16);
  {
    float4 a0 = *(const float4*)(s0p), a1 = *(const float4*)(s0p + 4);
    float4 b0 = *(const float4*)(q0p), b1 = *(const float4*)(q0p + 4);
    f16x8 o0;
    BUILD_S(o0, a0, a1, b0, b1);
    *(f16x8*)(As_base + rl0 * 32 + wchunk * 8) = o0;
  }
  __syncthreads();

  int cur = 0;
  for (int it = 0; it < 15; ++it) {
    const int nxt = cur ^ 1;
    const int kn = (it + 1) * 32;
    gload16(Bg + kn, Bs_base + nxt * 4096 + t * 16);
    float4 a0 = *(const float4*)(s0p + kn), a1 = *(const float4*)(s0p + kn + 4);
    float4 b0 = *(const float4*)(q0p + kn), b1 = *(const float4*)(q0p + kn + 4);
    {
      _Float16* As = As_base + cur * 2048;
      _Float16* Bs = (_Float16*)(Bs_base + cur * 4096);
      f16x8 fa[2], fb[2];
#pragma unroll
      for (int m = 0; m < 2; m++)
        fa[m] = *(const f16x8*)(As + (wm + m * 16 + lr) * 32 + rchunk);
#pragma unroll
      for (int n = 0; n < 2; n++)
        fb[n] = *(const f16x8*)(Bs + (wn + n * 16 + lr) * 32 + rchunk);
#pragma unroll
      for (int m = 0; m < 2; m++)
#pragma unroll
        for (int n = 0; n < 2; n++)
          acc[m][n] = __builtin_amdgcn_mfma_f32_16x16x32_f16(fa[m], fb[n], acc[m][n], 0, 0, 0);
    }
    {
      f16x8 o0;
      BUILD_S(o0, a0, a1, b0, b1);
      *(f16x8*)(As_base + nxt * 2048 + rl0 * 32 + wchunk * 8) = o0;
    }
    __syncthreads();
    cur = nxt;
  }
  {
    _Float16* As = As_base + cur * 2048;
    _Float16* Bs = (_Float16*)(Bs_base + cur * 4096);
    f16x8 fa[2], fb[2];
#pragma unroll
    for (int m = 0; m < 2; m++)
      fa[m] = *(const f16x8*)(As + (wm + m * 16 + lr) * 32 + rchunk);
#pragma unroll
    for (int n = 0; n < 2; n++)
      fb[n] = *(const f16x8*)(Bs + (wn + n * 16 + lr) * 32 + rchunk);
#pragma unroll
    for (int m = 0; m < 2; m++)
#pragma unroll
      for (int n = 0; n < 2; n++)
        acc[m][n] = __builtin_amdgcn_mfma_f32_16x16x32_f16(fa[m], fb[n], acc[m][n], 0, 0, 0);
  }

  // fused-dot epilogue: partial logit over this block's 64 cols
  float bf1v[2], wf2v[2];
#pragma unroll
  for (int n = 0; n < 2; n++) {
    int col = tn * 64 + wn + n * 16 + lr;
    bf1v[n] = bf1[col];
    wf2v[n] = Wf2[col];
  }
#pragma unroll
  for (int m = 0; m < 2; m++) {
#pragma unroll
    for (int reg = 0; reg < 4; reg++) {
      float p = 0.0f;
#pragma unroll
      for (int n = 0; n < 2; n++)
        p += fmaxf(acc[m][n][reg] + bf1v[n], 0.0f) * wf2v[n];
      p += __shfl_xor(p, 1);
      p += __shfl_xor(p, 2);
      p += __shfl_xor(p, 4);
      p += __shfl_xor(p, 8);
      if (lr == 0) {
        int row = tm * 64 + wm + m * 16 + lg * 4 + reg;
        atomicAdd(&out[row], p);
      }
    }
  }
#undef BUILD_S
}

// ---------------------------------------------------------------------------
extern "C" void kernel_launch(void* const* d_in, const int* in_sizes, int n_in,
                              void* d_out, int out_size, void* d_ws, size_t ws_size,
                              hipStream_t stream) {
  const float* xs  = (const float*)d_in[0];
  const float* xq  = (const float*)d_in[1];
  const float* Wg1 = (const float*)d_in[2];
  const float* bg1 = (const float*)d_in[3];
  const float* Wg2 = (const float*)d_in[4];
  const float* bg2 = (const float*)d_in[5];
  const float* Wf1 = (const float*)d_in[6];
  const float* bf1 = (const float*)d_in[7];
  const float* Wf2 = (const float*)d_in[8];
  const float* bf2 = (const float*)d_in[9];
  float* out = (float*)d_out;

  char* ws = (char*)d_ws;
  _Float16* Wg1T = (_Float16*)(ws);             // 1,048,576
  _Float16* Wg2T = (_Float16*)(ws + 1048576);   //   524,288
  _Float16* Wf1T = (_Float16*)(ws + 1572864);   //   524,288
  _Float16* UVh  = (_Float16*)(ws + 2097152);   // 3,670,016
  float*    SSs  = (float*)(ws + 5767168);      //   262,144
  float*    SQs  = (float*)(ws + 6029312);      // 4,194,304

  convert_t<<<512, 256, 0, stream>>>(Wg1, Wg2, Wf1, bf2, Wg1T, Wg2T, Wf1T, out);
  gemm1_fused<<<448, 256, 0, stream>>>(xs, xq, Wg1T, bg1, UVh);
  gemm2_fused<<<1152, 256, 0, stream>>>(UVh, Wg2T, bg2, SSs, SQs);
  gemm3_fused<<<256, 256, 0, stream>>>(SSs, SQs, Wf1T, bf1, Wf2, out);
}